// Round 6
// baseline (1874.294 us; speedup 1.0000x reference)
//
#include <hip/hip_runtime.h>
#include <math.h>

#define BB 16
#define CC 192
#define NF 192
#define HH 128
#define WW 128
#define G4 768
#define KTOT 768
#define LDA 776                 // A LDS row stride in shorts (768 + 8 pad)
#define NJB 12                  // j-blocks (NF/16)
#define GRIDSZ (NJB * BB)       // 192 blocks
#define RED_STRIDE 36           // f32 per lane in reduction buffer (32 + 4 pad)
#define SMEM_BYTES (64 * LDA * 2 + 4 * 64 * RED_STRIDE * 4)

typedef __bf16 bf16x8 __attribute__((ext_vector_type(8)));
typedef float  f32x4  __attribute__((ext_vector_type(4)));
typedef float  f32x16 __attribute__((ext_vector_type(16)));

// Per-batch MONOTONIC arrival counter (12 arrivals/step, never reset mid-kernel).
// Relaxed agent atomics only. Slots 256B apart. Zeroed each launch by prep_weights.
__device__ unsigned g_cnt[BB * 64];

__device__ __forceinline__ float hsig(float v) {
    float y = fmaf(0.2f, v, 0.5f);
    return fminf(fmaxf(y, 0.f), 1.f);
}

// tanh(x) = 1 - 2/(e^{2x}+1); e^{2x} = 2^(2*log2e*x). Clamp to +-8. Compiler
// builtins (hazards handled). ~1e-6 abs error << bf16 noise floor.
__device__ __forceinline__ float tanh_fast(float x) {
    float y = fminf(fmaxf(x, -8.f), 8.f) * 2.885390082f;   // 2*log2(e)
    float e = __builtin_amdgcn_exp2f(y);
    float r = __builtin_amdgcn_rcpf(e + 1.f);
    return fmaf(-2.f, r, 1.f);
}

__device__ __forceinline__ unsigned short f2bf(float f) {
    unsigned int u = __float_as_uint(f);
    u += 0x7fffu + ((u >> 16) & 1u);   // RNE
    return (unsigned short)(u >> 16);
}

// Wc[row=g*NF+j][k]: k<192 masked input weights; k=192+d*192+c = U tap d.
__global__ void prep_weights(const float* __restrict__ Wf,
                             const float* __restrict__ Uf,
                             unsigned short* __restrict__ Wc) {
    int idx = blockIdx.x * blockDim.x + threadIdx.x;
    if (idx < BB)                        // reset per-batch counters each launch
        g_cnt[idx * 64] = 0u;
    if (idx >= G4 * KTOT) return;
    int row = idx / KTOT;
    int k   = idx - row * KTOT;
    float v;
    if (k < CC) {
        int lim = row < 64 ? 64 : (row < 128 ? 128 : 192);
        v = (k < lim) ? Wf[row * CC + k] : 0.f;
    } else {
        int kp = k - CC;
        int d  = kp / CC;
        int c  = kp - d * CC;
        v = Uf[((size_t)row * CC + c) * 3 + d];
    }
    Wc[idx] = f2bf(v);
}

// x-part of Bsrc: Bsrc[t][b][w][c] = bf16(x[b][c][t][w]), c in [0,192).
__global__ void prep_bx(const float* __restrict__ x, unsigned short* __restrict__ Bsrc) {
    int idx = blockIdx.x * blockDim.x + threadIdx.x;   // over 128*16*128
    if (idx >= HH * BB * WW) return;
    int w = idx & (WW - 1);
    int r = idx >> 7;
    int b = r & (BB - 1);
    int t = r >> 4;
    const float* xp = x + ((size_t)b * CC * HH + t) * WW + w;
    unsigned short* dp = Bsrc + (size_t)idx * KTOT;
#pragma unroll
    for (int cc = 0; cc < CC / 8; ++cc) {
        unsigned short v[8];
#pragma unroll
        for (int i = 0; i < 8; ++i)
            v[i] = f2bf(xp[(size_t)(cc * 8 + i) * (HH * WW)]);
        *(uint4*)(dp + cc * 8) = *(uint4*)v;
    }
}

// Zero the never-written halo slots for all t: [t][b][0][192..384) and [t][b][127][576..768).
__global__ void prep_bh_oob(unsigned short* __restrict__ Bsrc) {
    int idx = blockIdx.x * blockDim.x + threadIdx.x;   // 128*16*384
    if (idx >= HH * BB * 384) return;
    int u = idx % 384;
    int r = idx / 384;
    int b = r & (BB - 1);
    int t = r >> 4;
    size_t base = ((size_t)(t * BB + b) * WW) * KTOT;
    size_t off = (u < 192) ? (size_t)0 * KTOT + 192 + u
                           : (size_t)127 * KTOT + 384 + u;   // 576 + (u-192)
    Bsrc[base + off] = 0;
}

// t=0 h-part from init_h: Bsrc[0][b][w][192+d*192+c] = init_h[c][w+d-1] (0 if OOB).
__global__ void prep_bh0(const float* __restrict__ init_h, unsigned short* __restrict__ Bsrc) {
    int idx = blockIdx.x * blockDim.x + threadIdx.x;   // 16*128*576
    if (idx >= BB * WW * 576) return;
    int kp = idx % 576;
    int r  = idx / 576;
    int w  = r & (WW - 1);
    int b  = r >> 7;
    int d  = kp / CC;
    int c  = kp - d * CC;
    int wt = w + d - 1;
    float v = (wt >= 0 && wt < WW) ? init_h[c * WW + wt] : 0.f;
    Bsrc[((size_t)b * WW + w) * KTOT + CC + kp] = f2bf(v);
}

// Persistent LSTM: 192 blocks x 512 threads (8 waves = 2/SIMD).
// 32x32x16 MFMA restructure (halves LDS A-traffic, the measured bottleneck):
//   waves 0-3 (grp0): M=64 (4 gates x 16 j) x N=32 (w-strip), K = 0..383
//                     (x-part + U tap d0), acc init = bias.
//   waves 4-7 (grp1): same (M,N) tiles, K = 384..767 (taps d1,d2), acc = 0.
// Partials reduced through padded LDS; grp0 owns epilogue/scatter/out.
// C layout (HW-verified m74/m101): col=lane&31, row=(reg&3)+8*(reg>>2)+4*(lane>>5).
// Sync protocol identical to the round-5 kernel that passed.
__global__ __launch_bounds__(512, 1) void lstm_persist(
    const unsigned short* __restrict__ Wc,
    unsigned short* __restrict__ Bsrc,
    const float* __restrict__ bias,
    const float* __restrict__ init_c,
    float* __restrict__ out)
{
    extern __shared__ unsigned short smem[];
    unsigned short (*Alds)[LDA] = (unsigned short(*)[LDA])smem;
    float* red = (float*)(smem + 64 * LDA);   // [4 strips][64 lanes][RED_STRIDE]

    const int tid  = threadIdx.x;
    const int nw   = tid >> 6;
    const int lane = tid & 63;
    const int c31  = lane & 31;
    const int l5   = lane >> 5;
    const bool grp0 = (nw < 4);
    const int ws   = grp0 ? nw : nw - 4;    // w-strip 0..3
    const int w    = ws * 32 + c31;         // this lane's w column
    const int jb   = blockIdx.x % NJB;
    const int b    = blockIdx.x / NJB;
    const int j0   = jb * 16;
    unsigned* const cntp = &g_cnt[b * 64];

    // ---- load A once: row r -> Wc row (r>>4)*NF + j0 + (r&15) ----
    for (int u = tid; u < 64 * 96; u += 512) {
        int r  = u / 96;
        int ko = (u - r * 96) * 8;
        int grow = (r >> 4) * NF + j0 + (r & 15);
        *(uint4*)&Alds[r][ko] = *(const uint4*)(Wc + (size_t)grow * KTOT + ko);
    }

    // ---- bias & c-state (grp0 only); jq(r) = (r&3)+8*(r>>2)+4*l5, r in 0..7 ----
    float biasr[4][8];
    float creg[8];
    if (grp0) {
#pragma unroll
        for (int r = 0; r < 8; ++r) {
            const int jq = (r & 3) + 8 * (r >> 2) + 4 * l5;
#pragma unroll
            for (int g = 0; g < 4; ++g)
                biasr[g][r] = bias[g * NF + j0 + jq];
            creg[r] = init_c[(j0 + jq) * WW + w];
        }
    }
    __syncthreads();

    // ---- prefetch x-frags for t=0 (grp0) ----
    bf16x8 bxc[12], bxn[12];
    if (grp0) {
        const unsigned short* B0 = Bsrc + ((size_t)b * WW + w) * KTOT;
#pragma unroll
        for (int s = 0; s < 12; ++s)
            bxc[s] = *(const bf16x8*)(B0 + s * 16 + l5 * 8);
    }

    float hn[8];
    for (int t = 0; t < HH; ++t) {
        f32x16 acc0, acc1;   // tile0 = rows 0..31 (o,f), tile1 = rows 32..63 (i,g)
        if (grp0) {
#pragma unroll
            for (int r = 0; r < 8; ++r) {
                acc0[r] = biasr[0][r]; acc0[r + 8] = biasr[1][r];
                acc1[r] = biasr[2][r]; acc1[r + 8] = biasr[3][r];
            }
        } else {
#pragma unroll
            for (int i = 0; i < 16; ++i) { acc0[i] = 0.f; acc1[i] = 0.f; }
        }

        const unsigned short* Bn =
            Bsrc + ((size_t)(t * BB + b) * WW + w) * KTOT;

        // ---- grp0 pre-spin: x-part (k-steps 0..11, prep data only) ----
        if (grp0) {
#pragma unroll
            for (int s = 0; s < 12; ++s) {
                const int k = s * 16 + l5 * 8;
                bf16x8 a0 = *(const bf16x8*)&Alds[c31][k];
                bf16x8 a1 = *(const bf16x8*)&Alds[32 + c31][k];
                acc0 = __builtin_amdgcn_mfma_f32_32x32x16_bf16(a0, bxc[s], acc0, 0, 0, 0);
                acc1 = __builtin_amdgcn_mfma_f32_32x32x16_bf16(a1, bxc[s], acc1, 0, 0, 0);
            }
        }

        // ---- wait for all 12 j-blocks' h-scatter of this step ----
        if (t > 0) {
            const unsigned need = (unsigned)(NJB * t);
            while (__hip_atomic_load(cntp, __ATOMIC_RELAXED,
                                     __HIP_MEMORY_SCOPE_AGENT) < need)
                __builtin_amdgcn_s_sleep(1);
            __builtin_amdgcn_fence(__ATOMIC_ACQUIRE, "workgroup");
        }

        if (grp0) {
            // ---- d0 tap: k-steps 12..23 ----
            bf16x8 bd[12];
#pragma unroll
            for (int s = 0; s < 12; ++s)
                bd[s] = *(const bf16x8*)(Bn + 192 + s * 16 + l5 * 8);
            // prefetch next step's x-frags (issued after bd, so bd's wait
            // leaves them in flight under the MFMAs + epilogue)
            if (t < HH - 1) {
                const unsigned short* Bx = Bn + (size_t)BB * WW * KTOT;
#pragma unroll
                for (int s = 0; s < 12; ++s)
                    bxn[s] = *(const bf16x8*)(Bx + s * 16 + l5 * 8);
            }
#pragma unroll
            for (int s = 0; s < 12; ++s) {
                const int k = (12 + s) * 16 + l5 * 8;
                bf16x8 a0 = *(const bf16x8*)&Alds[c31][k];
                bf16x8 a1 = *(const bf16x8*)&Alds[32 + c31][k];
                acc0 = __builtin_amdgcn_mfma_f32_32x32x16_bf16(a0, bd[s], acc0, 0, 0, 0);
                acc1 = __builtin_amdgcn_mfma_f32_32x32x16_bf16(a1, bd[s], acc1, 0, 0, 0);
            }
        } else {
            // ---- d1,d2 taps: k-steps 24..47 ----
            bf16x8 bh[24];
#pragma unroll
            for (int s = 0; s < 24; ++s)
                bh[s] = *(const bf16x8*)(Bn + 384 + s * 16 + l5 * 8);
#pragma unroll
            for (int s = 0; s < 24; ++s) {
                const int k = (24 + s) * 16 + l5 * 8;
                bf16x8 a0 = *(const bf16x8*)&Alds[c31][k];
                bf16x8 a1 = *(const bf16x8*)&Alds[32 + c31][k];
                acc0 = __builtin_amdgcn_mfma_f32_32x32x16_bf16(a0, bh[s], acc0, 0, 0, 0);
                acc1 = __builtin_amdgcn_mfma_f32_32x32x16_bf16(a1, bh[s], acc1, 0, 0, 0);
            }
            // ---- publish partials (padded stride: uniform bank spread) ----
            float* rp = red + (size_t)(ws * 64 + lane) * RED_STRIDE;
#pragma unroll
            for (int rb = 0; rb < 4; ++rb) {
                f32x4 v0 = {acc0[4 * rb], acc0[4 * rb + 1], acc0[4 * rb + 2], acc0[4 * rb + 3]};
                f32x4 v1 = {acc1[4 * rb], acc1[4 * rb + 1], acc1[4 * rb + 2], acc1[4 * rb + 3]};
                *(f32x4*)(rp + 4 * rb)      = v0;
                *(f32x4*)(rp + 16 + 4 * rb) = v1;
            }
        }
        __syncthreads();   // R1: partials visible

        if (grp0) {
            // ---- reduce K-halves ----
            const float* rp = red + (size_t)(ws * 64 + lane) * RED_STRIDE;
#pragma unroll
            for (int rb = 0; rb < 4; ++rb) {
                f32x4 v0 = *(const f32x4*)(rp + 4 * rb);
                f32x4 v1 = *(const f32x4*)(rp + 16 + 4 * rb);
#pragma unroll
                for (int i = 0; i < 4; ++i) {
                    acc0[4 * rb + i] += v0[i];
                    acc1[4 * rb + i] += v1[i];
                }
            }
            // ---- epilogue: o=acc0[r], f=acc0[r+8], i=acc1[r], g=acc1[r+8] ----
#pragma unroll
            for (int r = 0; r < 8; ++r) {
                float og = hsig(acc0[r]);
                float fg = hsig(acc0[r + 8]);
                float ig = hsig(acc1[r]);
                float gg = tanh_fast(acc1[r + 8]);
                float cn = fmaf(fg, creg[r], ig * gg);
                creg[r] = cn;
                hn[r] = og * tanh_fast(cn);
            }
            // ---- scatter h (2 packs x 3 taps, 8B agent stores) ----
            if (t < HH - 1) {
                unsigned long long pk0 =
                      (unsigned long long)f2bf(hn[0])
                    | ((unsigned long long)f2bf(hn[1]) << 16)
                    | ((unsigned long long)f2bf(hn[2]) << 32)
                    | ((unsigned long long)f2bf(hn[3]) << 48);
                unsigned long long pk1 =
                      (unsigned long long)f2bf(hn[4])
                    | ((unsigned long long)f2bf(hn[5]) << 16)
                    | ((unsigned long long)f2bf(hn[6]) << 32)
                    | ((unsigned long long)f2bf(hn[7]) << 48);
                unsigned short* Bns =
                    Bsrc + ((size_t)((t + 1) * BB + b) * WW) * KTOT;
                const int joA = CC + j0 + 4 * l5;        // jq 0..3
                const int joB = joA + 8;                 // jq 8..11
                // tap d: dest row w2 = w + 1 - d
                __hip_atomic_store((unsigned long long*)
                    (Bns + (size_t)w * KTOT + joA + CC), pk0,
                    __ATOMIC_RELAXED, __HIP_MEMORY_SCOPE_AGENT);          // d=1
                __hip_atomic_store((unsigned long long*)
                    (Bns + (size_t)w * KTOT + joB + CC), pk1,
                    __ATOMIC_RELAXED, __HIP_MEMORY_SCOPE_AGENT);
                if (w < WW - 1) {
                    __hip_atomic_store((unsigned long long*)
                        (Bns + (size_t)(w + 1) * KTOT + joA), pk0,
                        __ATOMIC_RELAXED, __HIP_MEMORY_SCOPE_AGENT);      // d=0
                    __hip_atomic_store((unsigned long long*)
                        (Bns + (size_t)(w + 1) * KTOT + joB), pk1,
                        __ATOMIC_RELAXED, __HIP_MEMORY_SCOPE_AGENT);
                }
                if (w > 0) {
                    __hip_atomic_store((unsigned long long*)
                        (Bns + (size_t)(w - 1) * KTOT + joA + 2 * CC), pk0,
                        __ATOMIC_RELAXED, __HIP_MEMORY_SCOPE_AGENT);      // d=2
                    __hip_atomic_store((unsigned long long*)
                        (Bns + (size_t)(w - 1) * KTOT + joB + 2 * CC), pk1,
                        __ATOMIC_RELAXED, __HIP_MEMORY_SCOPE_AGENT);
                }
            }
        }

        if (t < HH - 1) {
            // grp0 drains its scatter stores to the coherence point; the block
            // barrier then orders all waves before tid 0 publishes arrival.
            if (grp0)
                asm volatile("s_waitcnt vmcnt(0)" ::: "memory");
            __syncthreads();   // R2
            if (tid == 0)
                __hip_atomic_fetch_add(cntp, 1u, __ATOMIC_RELAXED,
                                       __HIP_MEMORY_SCOPE_AGENT);
        }

        // ---- out[] stores off the arrival critical path ----
        if (grp0) {
#pragma unroll
            for (int r = 0; r < 8; ++r) {
                const int jq = (r & 3) + 8 * (r >> 2) + 4 * l5;
                out[(((size_t)b * NF + j0 + jq) * HH + t) * WW + w] = hn[r];
            }
#pragma unroll
            for (int s = 0; s < 12; ++s)
                bxc[s] = bxn[s];
        }
    }
}

extern "C" void kernel_launch(void* const* d_in, const int* in_sizes, int n_in,
                              void* d_out, int out_size, void* d_ws, size_t ws_size,
                              hipStream_t stream) {
    const float* x      = (const float*)d_in[0];
    const float* W_iof  = (const float*)d_in[1];
    const float* U_iof  = (const float*)d_in[2];
    const float* b_iof  = (const float*)d_in[3];
    const float* init_h = (const float*)d_in[4];
    const float* init_c = (const float*)d_in[5];
    float* out = (float*)d_out;

    unsigned short* Wc   = (unsigned short*)d_ws;                       // 768*768 bf16
    unsigned short* Bsrc = Wc + (size_t)G4 * KTOT;                      // 128*16*128*768 bf16

    prep_weights<<<(G4 * KTOT + 255) / 256, 256, 0, stream>>>(W_iof, U_iof, Wc);
    prep_bx<<<(HH * BB * WW + 255) / 256, 256, 0, stream>>>(x, Bsrc);
    prep_bh_oob<<<(HH * BB * 384 + 255) / 256, 256, 0, stream>>>(Bsrc);
    prep_bh0<<<(BB * WW * 576 + 255) / 256, 256, 0, stream>>>(init_h, Bsrc);

    const unsigned short* Wcp = Wc;
    unsigned short* Bsp = Bsrc;
    const float* bp = b_iof;
    const float* icp = init_c;
    float* op = out;
    void* args[] = {&Wcp, &Bsp, &bp, &icp, &op};
    // Cooperative launch: co-residency guarantee for the spin barriers.
    hipLaunchCooperativeKernel((const void*)lstm_persist, dim3(GRIDSZ), dim3(512),
                               args, SMEM_BYTES, stream);
}